// Round 1
// 1066.505 us; speedup vs baseline: 1.5290x; 1.5290x over previous
//
#include <hip/hip_runtime.h>

namespace {

typedef __attribute__((ext_vector_type(4))) _Float16 half4v;
typedef __attribute__((ext_vector_type(4))) float   float4v;
typedef unsigned int u32;

#define MFMA16(a,b,c) __builtin_amdgcn_mfma_f32_16x16x16f16((a),(b),(c),0,0,0)

constexpr int Bb = 2048;
constexpr int Tt = 512;
constexpr float LOG2PI_ = 1.8378770664093453f;

struct InPtrs { const float* p[42]; };

__device__ __forceinline__ float rcpf(float x){ return __builtin_amdgcn_rcpf(x); }
__device__ __forceinline__ float sigm(float x){ return rcpf(1.0f + __expf(-x)); }
__device__ __forceinline__ float tanh_(float x){ return 1.0f - 2.0f*rcpf(1.0f + __expf(2.0f*x)); }

// LDS-only barrier: waits lgkmcnt(0) but does NOT drain vmcnt, so global
// prefetch loads / streaming stores stay in flight across the barrier.
// All cross-wave traffic in these kernels goes through LDS (lgkmcnt-tracked),
// so this is sufficient for correctness.
__device__ __forceinline__ void barrier_lds(){
  asm volatile("s_waitcnt lgkmcnt(0)" ::: "memory");
  __builtin_amdgcn_s_barrier();
  asm volatile("" ::: "memory");
}

__global__ void zero2(float* out){ if (threadIdx.x < 2) out[threadIdx.x] = 0.f; }

__device__ __forceinline__ void gru_update(const float4v& Dr, const float4v& Dz,
                                           const float4v& Dn, const float4v& Dh, half4v& hB){
  #pragma unroll
  for (int i = 0; i < 4; ++i){
    const float rr = sigm(Dr[i]);
    const float zz = sigm(Dz[i]);
    const float nn = tanh_(Dn[i] + rr*Dh[i]);
    const float hp = (float)hB[i];
    hB[i] = (_Float16)((1.f - zz)*nn + zz*hp);
  }
}

__device__ __forceinline__ half4v relu_pack(const float4v& D){
  half4v o;
  #pragma unroll
  for (int i = 0; i < 4; ++i) o[i] = (_Float16)fmaxf(D[i], 0.f);
  return o;
}

// ================= Phase 1: bi-GRU, producer/consumer =================
// grid (128, 2) x 128 threads. Wave1 produces gi = Wih@x + biases for chunk c into
// buffer c&1; LDS barrier; wave0 consumes chunk c while wave1 produces c+1.
// x prefetch is an 8-step register ring (statically indexed: tg%8 == st), so
// ~32 global loads stay in flight across steps AND across the (lgkm-only) barrier.
constexpr int CH = 8;
constexpr int NCH = Tt / CH;   // 64

__global__ __launch_bounds__(128,1) void bigru(InPtrs ip, _Float16* __restrict__ hf,
                                               _Float16* __restrict__ hb)
{
  const int tid = threadIdx.x;
  const int w = tid >> 6;
  const int l = tid & 63, r = l & 15, q = l >> 4;
  const int dir = blockIdx.y;
  const int base = blockIdx.x * 16;

  const float* __restrict__ x   = ip.p[0];
  const float* __restrict__ Wih = dir ? ip.p[6] : ip.p[2];
  const float* __restrict__ Whh = dir ? ip.p[7] : ip.p[3];
  const float* __restrict__ bih = dir ? ip.p[8] : ip.p[4];
  const float* __restrict__ bhh = dir ? ip.p[9] : ip.p[5];
  _Float16* __restrict__ hout = dir ? hb : hf;

  __shared__ __align__(16) float giS[2][CH][64][12];   // 48 KB

  // ---- per-wave persistent state (loaded divergently; NO barriers in branches) ----
  half4v Wi[3][4];            // producer
  float  b0[4], b1[4], b2[4];
  float4v xp[CH][4];          // 8-step prefetch ring (128 VGPR, producer only)
  half4v Wh[3];               // consumer
  float  bh2[4];
  half4v hB = {0,0,0,0};
  const float* xrow = x + (size_t)(base + r) * Tt * 64;

  if (w == 1){
    #pragma unroll
    for (int rt = 0; rt < 3; ++rt)
      #pragma unroll
      for (int kt = 0; kt < 4; ++kt)
        #pragma unroll
        for (int j = 0; j < 4; ++j)
          Wi[rt][kt][j] = (_Float16)Wih[(rt*16 + r)*64 + kt*16 + q*4 + j];
    #pragma unroll
    for (int i = 0; i < 4; ++i){
      const int row = q*4 + i;
      b0[i] = bih[row]      + bhh[row];
      b1[i] = bih[16 + row] + bhh[16 + row];
      b2[i] = bih[32 + row];
    }
    // preload steps 0..7 into the ring
    #pragma unroll
    for (int s = 0; s < CH; ++s){
      const int tn = dir ? Tt-1-s : s;
      #pragma unroll
      for (int kt = 0; kt < 4; ++kt)
        xp[s][kt] = *(const float4v*)(xrow + (size_t)tn*64 + kt*16 + q*4);
    }
  } else {
    #pragma unroll
    for (int rt = 0; rt < 3; ++rt)
      #pragma unroll
      for (int j = 0; j < 4; ++j)
        Wh[rt][j] = (_Float16)Whh[(rt*16 + r)*16 + q*4 + j];
    #pragma unroll
    for (int i = 0; i < 4; ++i) bh2[i] = bhh[32 + q*4 + i];
  }

  for (int c = 0; c < NCH; ++c){
    if (w == 1){
      // ---- produce chunk c ----
      #pragma unroll
      for (int st = 0; st < CH; ++st){
        const int tg = c*CH + st;       // ring slot = tg % 8 == st (static)
        half4v xB[4];
        #pragma unroll
        for (int kt = 0; kt < 4; ++kt)
          #pragma unroll
          for (int j = 0; j < 4; ++j) xB[kt][j] = (_Float16)xp[st][kt][j];
        const int tp = tg + CH;         // refill slot with step tg+8
        if (tp < Tt){
          const int tn = dir ? Tt-1-tp : tp;
          #pragma unroll
          for (int kt = 0; kt < 4; ++kt)
            xp[st][kt] = *(const float4v*)(xrow + (size_t)tn*64 + kt*16 + q*4);
        }
        float4v A0 = {b0[0],b0[1],b0[2],b0[3]};
        float4v A1 = {b1[0],b1[1],b1[2],b1[3]};
        float4v A2 = {b2[0],b2[1],b2[2],b2[3]};
        #pragma unroll
        for (int kt = 0; kt < 4; ++kt){
          A0 = MFMA16(Wi[0][kt], xB[kt], A0);
          A1 = MFMA16(Wi[1][kt], xB[kt], A1);
          A2 = MFMA16(Wi[2][kt], xB[kt], A2);
        }
        float* o = &giS[c&1][st][l][0];
        *(float4v*)(o + 0) = A0;
        *(float4v*)(o + 4) = A1;
        *(float4v*)(o + 8) = A2;
      }
    }
    barrier_lds();            // block-uniform, lgkm-only
    if (w == 0){
      // ---- consume chunk c (overlaps produce of chunk c+1) ----
      for (int st = 0; st < CH; ++st){
        const int tg = c*CH + st;
        const int t = dir ? Tt-1-tg : tg;
        const float* gi = &giS[c&1][st][l][0];
        float4v A0 = *(const float4v*)(gi + 0);
        float4v A1 = *(const float4v*)(gi + 4);
        float4v A2 = *(const float4v*)(gi + 8);
        float4v Dh = {bh2[0],bh2[1],bh2[2],bh2[3]};
        A0 = MFMA16(Wh[0], hB, A0);
        A1 = MFMA16(Wh[1], hB, A1);
        Dh = MFMA16(Wh[2], hB, Dh);
        gru_update(A0, A1, A2, Dh, hB);
        *(half4v*)(hout + (((size_t)t*Bb + base + r) << 4) + q*4) = hB;
      }
    }
  }
}

// ================= Phase 3a: sequential VAE recurrences only =================
// grid 128 x 192 threads, 3-wave skewed pipeline, one lgkm-only barrier/iter.
// Wave A (step i): infz GRU + inf head + z (head is needed in-chain for z_t);
//                  stores h_z (fp16) for the KL epilogue.
// Wave B (step i-1): genz GRU only; stores h_gz.
// Wave C (step i-2): genr GRU only; stores h_gr.
// All heads / KL / NLL are recomputed bit-identically in parallel epilogues
// (they consume the same fp16 hidden states through the same fp16 weights).
__global__ __launch_bounds__(192,1) void vae_seq(InPtrs ip, const _Float16* __restrict__ hf,
                                                 const _Float16* __restrict__ hb,
                                                 _Float16* __restrict__ hz,
                                                 _Float16* __restrict__ hgz,
                                                 _Float16* __restrict__ hgr)
{
  const int tid = threadIdx.x;
  const int w = tid / 64;
  const int l = tid & 63, r = l & 15, q = l >> 4;
  const int base = blockIdx.x * 16;
  const int row0 = q*4;

  __shared__ u32 zS[3][2][64];
  for (int i = tid; i < 3*2*64; i += 192) ((u32*)zS)[i] = 0u;
  barrier_lds();

  // ---- per-wave persistent state ----
  // wave A
  half4v WizA[3][3], WhzA[3], I1A, I2A, IMuA, ICovA;
  float bz0[4], bz1[4], bzn[4], bzh[4], bI1v[4], bI2v[4], bIMu[4], bICov[4];
  half4v hzB = {0,0,0,0}, zB = {0,0,0,0};
  half4v hrN = {0,0,0,0}, hlN = {0,0,0,0};
  float eN[4];
  // wave B
  half4v WgzA[3], WhgzA[3];
  float bg0[4], bg1[4], bgn[4], bgh[4];
  half4v hgzB = {0,0,0,0};
  // wave C
  half4v WgrA[3], WhgrA[3];
  float br0[4], br1[4], brn[4], brh[4];
  half4v hgrB = {0,0,0,0};

  const float* erow = ip.p[1] + (size_t)(base + r) * Tt * 10;

  if (w == 0){
    #pragma unroll
    for (int rt = 0; rt < 3; ++rt)
      #pragma unroll
      for (int kt = 0; kt < 3; ++kt)
        #pragma unroll
        for (int j = 0; j < 4; ++j){
          const int k = kt*16 + q*4 + j;
          int c;
          if (kt == 0) c = (k < 10) ? k : -1;
          else if (kt == 1) c = 10 + (k - 16);
          else c = 26 + (k - 32);
          WizA[rt][kt][j] = (c >= 0) ? (_Float16)ip.p[10][(rt*16 + r)*42 + c] : (_Float16)0.f;
        }
    #pragma unroll
    for (int rt = 0; rt < 3; ++rt)
      #pragma unroll
      for (int j = 0; j < 4; ++j)
        WhzA[rt][j] = (_Float16)ip.p[11][(rt*16 + r)*16 + q*4 + j];
    #pragma unroll
    for (int j = 0; j < 4; ++j){
      const int k = q*4 + j;
      I1A[j]  = (_Float16)ip.p[14][r*16 + k];
      I2A[j]  = (_Float16)ip.p[16][r*16 + k];
      IMuA[j] = (r < 10) ? (_Float16)ip.p[18][r*16 + k] : (_Float16)0.f;
      ICovA[j]= (r < 10) ? (_Float16)ip.p[20][r*16 + k] : (_Float16)0.f;
    }
    #pragma unroll
    for (int i = 0; i < 4; ++i){
      const int row = row0 + i;
      bz0[i] = ip.p[12][row]    + ip.p[13][row];
      bz1[i] = ip.p[12][16+row] + ip.p[13][16+row];
      bzn[i] = ip.p[12][32+row];
      bzh[i] = ip.p[13][32+row];
      bI1v[i] = ip.p[15][row];  bI2v[i] = ip.p[17][row];
      bIMu[i]  = (row < 10) ? ip.p[19][row] : 0.f;
      bICov[i] = (row < 10) ? ip.p[21][row] : 0.f;
    }
    hlN = *(const half4v*)(hb + (((size_t)1*Bb + base + r) << 4) + q*4);
    #pragma unroll
    for (int i = 0; i < 4; ++i) eN[i] = (row0 + i < 10) ? erow[row0 + i] : 0.f;
  } else if (w == 1){
    #pragma unroll
    for (int rt = 0; rt < 3; ++rt)
      #pragma unroll
      for (int j = 0; j < 4; ++j){
        const int k = q*4 + j;
        WgzA[rt][j]  = (k < 10) ? (_Float16)ip.p[22][(rt*16 + r)*10 + k] : (_Float16)0.f;
        WhgzA[rt][j] = (_Float16)ip.p[23][(rt*16 + r)*16 + k];
      }
    #pragma unroll
    for (int i = 0; i < 4; ++i){
      const int row = row0 + i;
      bg0[i] = ip.p[24][row]    + ip.p[25][row];
      bg1[i] = ip.p[24][16+row] + ip.p[25][16+row];
      bgn[i] = ip.p[24][32+row];
      bgh[i] = ip.p[25][32+row];
    }
  } else {
    #pragma unroll
    for (int rt = 0; rt < 3; ++rt)
      #pragma unroll
      for (int j = 0; j < 4; ++j){
        const int k = q*4 + j;
        WgrA[rt][j]  = (k < 10) ? (_Float16)ip.p[34][(rt*16 + r)*10 + k] : (_Float16)0.f;
        WhgrA[rt][j] = (_Float16)ip.p[35][(rt*16 + r)*16 + k];
      }
    #pragma unroll
    for (int i = 0; i < 4; ++i){
      const int row = row0 + i;
      br0[i] = ip.p[36][row]    + ip.p[37][row];
      br1[i] = ip.p[36][16+row] + ip.p[37][16+row];
      brn[i] = ip.p[36][32+row];
      brh[i] = ip.p[37][32+row];
    }
  }

  // ---- single uniform pipeline loop: one lgkm-only barrier per iteration ----
  for (int i = 0; i < Tt + 2; ++i){
    if (w == 0){
      if (i < Tt){
        const half4v hrB = hrN, hlB = hlN;
        float ev[4];
        #pragma unroll
        for (int ii = 0; ii < 4; ++ii) ev[ii] = eN[ii];
        if (i < Tt-1){
          const int tn = i + 1;
          hrN = *(const half4v*)(hf + (((size_t)(tn-1)*Bb + base + r) << 4) + q*4);
          if (tn < Tt-1) hlN = *(const half4v*)(hb + (((size_t)(tn+1)*Bb + base + r) << 4) + q*4);
          else { half4v zz0 = {0,0,0,0}; hlN = zz0; }
          #pragma unroll
          for (int ii = 0; ii < 4; ++ii) eN[ii] = (row0 + ii < 10) ? erow[tn*10 + row0 + ii] : 0.f;
        }
        float4v Dr = {bz0[0],bz0[1],bz0[2],bz0[3]};
        float4v Dz = {bz1[0],bz1[1],bz1[2],bz1[3]};
        float4v Dn = {bzn[0],bzn[1],bzn[2],bzn[3]};
        float4v Dh = {bzh[0],bzh[1],bzh[2],bzh[3]};
        Dr = MFMA16(WizA[0][0], zB, Dr); Dr = MFMA16(WizA[0][1], hrB, Dr); Dr = MFMA16(WizA[0][2], hlB, Dr);
        Dz = MFMA16(WizA[1][0], zB, Dz); Dz = MFMA16(WizA[1][1], hrB, Dz); Dz = MFMA16(WizA[1][2], hlB, Dz);
        Dn = MFMA16(WizA[2][0], zB, Dn); Dn = MFMA16(WizA[2][1], hrB, Dn); Dn = MFMA16(WizA[2][2], hlB, Dn);
        Dr = MFMA16(WhzA[0], hzB, Dr);
        Dz = MFMA16(WhzA[1], hzB, Dz);
        Dh = MFMA16(WhzA[2], hzB, Dh);
        gru_update(Dr, Dz, Dn, Dh, hzB);
        // store h_z for the KL epilogue (same fp16 value the head consumes)
        *(half4v*)(hz + (((size_t)i*Bb + base + r) << 4) + q*4) = hzB;

        float4v H1 = {bI1v[0],bI1v[1],bI1v[2],bI1v[3]};
        H1 = MFMA16(I1A, hzB, H1);
        const half4v h1B = relu_pack(H1);
        float4v H2 = {bI2v[0],bI2v[1],bI2v[2],bI2v[3]};
        H2 = MFMA16(I2A, h1B, H2);
        const half4v h2B = relu_pack(H2);
        float4v Qmu  = {bIMu[0],bIMu[1],bIMu[2],bIMu[3]};
        float4v Qpre = {bICov[0],bICov[1],bICov[2],bICov[3]};
        Qmu  = MFMA16(IMuA,  h2B, Qmu);
        Qpre = MFMA16(ICovA, h2B, Qpre);

        const int slot = i % 3;
        #pragma unroll
        for (int ii = 0; ii < 4; ++ii){
          const float qs = __expf(Qpre[ii]);
          zB[ii] = (_Float16)(Qmu[ii] + qs*ev[ii]);
        }
        union { half4v h; u32 u[2]; } zc; zc.h = zB;
        zS[slot][0][l] = zc.u[0];
        zS[slot][1][l] = zc.u[1];
      }
    } else if (w == 1){
      if (i >= 1 && i <= Tt){
        const int s = i - 1;
        const int sp = (s - 1 + 3) % 3;
        union { half4v h; u32 u[2]; } zc;
        zc.u[0] = zS[sp][0][l]; zc.u[1] = zS[sp][1][l];
        const half4v zPrev = zc.h;

        float4v Er = {bg0[0],bg0[1],bg0[2],bg0[3]};
        float4v Ez = {bg1[0],bg1[1],bg1[2],bg1[3]};
        float4v En = {bgn[0],bgn[1],bgn[2],bgn[3]};
        float4v Eh = {bgh[0],bgh[1],bgh[2],bgh[3]};
        Er = MFMA16(WgzA[0], zPrev, Er); Er = MFMA16(WhgzA[0], hgzB, Er);
        Ez = MFMA16(WgzA[1], zPrev, Ez); Ez = MFMA16(WhgzA[1], hgzB, Ez);
        En = MFMA16(WgzA[2], zPrev, En);
        Eh = MFMA16(WhgzA[2], hgzB, Eh);
        gru_update(Er, Ez, En, Eh, hgzB);
        *(half4v*)(hgz + (((size_t)s*Bb + base + r) << 4) + q*4) = hgzB;
      }
    } else {
      if (i >= 2){
        const int u = i - 2;
        union { half4v h; u32 uu[2]; } zc;
        zc.uu[0] = zS[u % 3][0][l]; zc.uu[1] = zS[u % 3][1][l];
        const half4v zU = zc.h;

        float4v Fr = {br0[0],br0[1],br0[2],br0[3]};
        float4v Fz = {br1[0],br1[1],br1[2],br1[3]};
        float4v Fn = {brn[0],brn[1],brn[2],brn[3]};
        float4v Fh = {brh[0],brh[1],brh[2],brh[3]};
        Fr = MFMA16(WgrA[0], zU, Fr); Fr = MFMA16(WhgrA[0], hgrB, Fr);
        Fz = MFMA16(WgrA[1], zU, Fz); Fz = MFMA16(WhgrA[1], hgrB, Fz);
        Fn = MFMA16(WgrA[2], zU, Fn);
        Fh = MFMA16(WhgrA[2], hgrB, Fh);
        gru_update(Fr, Fz, Fn, Fh, hgrB);
        *(half4v*)(hgr + (((size_t)u*Bb + base + r) << 4) + q*4) = hgrB;
      }
    }
    barrier_lds();
  }
}

// ================= Phase 3b: parallel KL epilogue =================
// 65536 independent (tile,t) units; recomputes inf head (from h_z) and genz head
// (from h_gz) — bit-identical to the sequential path (same fp16 inputs/weights).
__global__ __launch_bounds__(256,4) void kl_epi(InPtrs ip, const _Float16* __restrict__ hz,
                                                const _Float16* __restrict__ hgz,
                                                float* __restrict__ out)
{
  const int tid = threadIdx.x;
  const int l = tid & 63, r = l & 15, q = l >> 4;
  const int row0 = q*4;
  const int wid = blockIdx.x * 4 + (tid >> 6);   // 4096 waves
  const int u0 = wid * 16;                       // 16 units/wave, contiguous t

  half4v I1A, I2A, IMuA, ICovA, Z1A, Z2A, ZMuA, ZCovA;
  float bI1v[4], bI2v[4], bIMu[4], bICov[4], bZ1v[4], bZ2v[4], bZMu[4], bZCov[4];
  #pragma unroll
  for (int j = 0; j < 4; ++j){
    const int k = q*4 + j;
    I1A[j]  = (_Float16)ip.p[14][r*16 + k];
    I2A[j]  = (_Float16)ip.p[16][r*16 + k];
    IMuA[j] = (r < 10) ? (_Float16)ip.p[18][r*16 + k] : (_Float16)0.f;
    ICovA[j]= (r < 10) ? (_Float16)ip.p[20][r*16 + k] : (_Float16)0.f;
    Z1A[j]  = (_Float16)ip.p[26][r*16 + k];
    Z2A[j]  = (_Float16)ip.p[28][r*16 + k];
    ZMuA[j] = (r < 10) ? (_Float16)ip.p[30][r*16 + k] : (_Float16)0.f;
    ZCovA[j]= (r < 10) ? (_Float16)ip.p[32][r*16 + k] : (_Float16)0.f;
  }
  #pragma unroll
  for (int i = 0; i < 4; ++i){
    const int row = row0 + i;
    bI1v[i] = ip.p[15][row];  bI2v[i] = ip.p[17][row];
    bIMu[i]  = (row < 10) ? ip.p[19][row] : 0.f;
    bICov[i] = (row < 10) ? ip.p[21][row] : 0.f;
    bZ1v[i] = ip.p[27][row];  bZ2v[i] = ip.p[29][row];
    bZMu[i]  = (row < 10) ? ip.p[31][row] : 0.f;
    bZCov[i] = (row < 10) ? ip.p[33][row] : 0.f;
  }

  float kl_acc = 0.f;
  for (int k = 0; k < 16; ++k){
    const int u = u0 + k;
    const int tile = u >> 9, t = u & 511;
    const size_t off = (((size_t)t*Bb + tile*16 + r) << 4) + q*4;
    const half4v hzB  = *(const half4v*)(hz  + off);
    const half4v hgzB = *(const half4v*)(hgz + off);

    float4v H1 = {bI1v[0],bI1v[1],bI1v[2],bI1v[3]};
    H1 = MFMA16(I1A, hzB, H1);
    const half4v h1B = relu_pack(H1);
    float4v H2 = {bI2v[0],bI2v[1],bI2v[2],bI2v[3]};
    H2 = MFMA16(I2A, h1B, H2);
    const half4v h2B = relu_pack(H2);
    float4v Qmu  = {bIMu[0],bIMu[1],bIMu[2],bIMu[3]};
    float4v Qpre = {bICov[0],bICov[1],bICov[2],bICov[3]};
    Qmu  = MFMA16(IMuA,  h2B, Qmu);
    Qpre = MFMA16(ICovA, h2B, Qpre);

    float4v G1 = {bZ1v[0],bZ1v[1],bZ1v[2],bZ1v[3]};
    G1 = MFMA16(Z1A, hgzB, G1);
    const half4v g1B = relu_pack(G1);
    float4v G2 = {bZ2v[0],bZ2v[1],bZ2v[2],bZ2v[3]};
    G2 = MFMA16(Z2A, g1B, G2);
    const half4v g2B = relu_pack(G2);
    float4v Pmu  = {bZMu[0],bZMu[1],bZMu[2],bZMu[3]};
    float4v Ppre = {bZCov[0],bZCov[1],bZCov[2],bZCov[3]};
    Pmu  = MFMA16(ZMuA,  g2B, Pmu);
    Ppre = MFMA16(ZCovA, g2B, Ppre);

    #pragma unroll
    for (int ii = 0; ii < 4; ++ii){
      const float qs = __expf(Qpre[ii]);
      const float dm = Qmu[ii] - Pmu[ii];
      kl_acc += (Ppre[ii] - Qpre[ii]) + (qs*qs + dm*dm)*0.5f*__expf(-2.f*Ppre[ii]) - 0.5f;
    }
  }
  #pragma unroll
  for (int m = 1; m < 64; m <<= 1) kl_acc += __shfl_xor(kl_acc, m, 64);
  if (l == 0) atomicAdd(&out[1], kl_acc * (1.f/(float)Bb));
}

// ================= Phase 3c: parallel NLL epilogue =================
// Recomputes genr head from h_gr (bit-identical) + low-rank Gaussian NLL vs x.
__global__ __launch_bounds__(256,2) void nll_epi(InPtrs ip, const _Float16* __restrict__ hgr,
                                                 float* __restrict__ out)
{
  const int tid = threadIdx.x;
  const int l = tid & 63, r = l & 15, q = l >> 4;
  const int row0 = q*4;
  const int wid = blockIdx.x * 4 + (tid >> 6);   // 4096 waves
  const int u0 = wid * 16;                       // 16 units/wave, contiguous t

  half4v R1A, R2A[12];
  float bR1v[4], bR2v[12][4];
  #pragma unroll
  for (int j = 0; j < 4; ++j){
    const int k = q*4 + j;
    R1A[j] = (_Float16)ip.p[38][r*16 + k];
    #pragma unroll
    for (int m = 0; m < 12; ++m)
      R2A[m][j] = (_Float16)ip.p[40][(m*16 + r)*16 + k];
  }
  #pragma unroll
  for (int i = 0; i < 4; ++i){
    const int row = row0 + i;
    bR1v[i] = ip.p[39][row];
    #pragma unroll
    for (int m = 0; m < 12; ++m) bR2v[m][i] = ip.p[41][m*16 + row];
  }

  float nll_acc = 0.f;
  for (int k = 0; k < 16; ++k){
    const int u = u0 + k;
    const int tile = u >> 9, t = u & 511;
    const half4v hgrB = *(const half4v*)(hgr + (((size_t)t*Bb + tile*16 + r) << 4) + q*4);
    const float* xrow = ip.p[0] + ((size_t)(tile*16 + r) * Tt + t) * 64;
    float4v xv[4];
    #pragma unroll
    for (int m = 0; m < 4; ++m) xv[m] = *(const float4v*)(xrow + m*16 + q*4);

    float4v R1D = {bR1v[0],bR1v[1],bR1v[2],bR1v[3]};
    R1D = MFMA16(R1A, hgrB, R1D);
    const half4v r1B = relu_pack(R1D);

    float s1 = 0.f, s2 = 0.f, s3 = 0.f, s4 = 0.f;
    #pragma unroll
    for (int m = 0; m < 4; ++m){
      float4v Dmu = {bR2v[m][0],bR2v[m][1],bR2v[m][2],bR2v[m][3]};
      float4v Ddp = {bR2v[4+m][0],bR2v[4+m][1],bR2v[4+m][2],bR2v[4+m][3]};
      float4v Dw  = {bR2v[8+m][0],bR2v[8+m][1],bR2v[8+m][2],bR2v[8+m][3]};
      Dmu = MFMA16(R2A[m],   r1B, Dmu);
      Ddp = MFMA16(R2A[4+m], r1B, Ddp);
      Dw  = MFMA16(R2A[8+m], r1B, Dw);
      #pragma unroll
      for (int ii = 0; ii < 4; ++ii){
        const float diag = __expf(Ddp[ii]) + 1e-4f;
        const float dinv = rcpf(diag);
        const float delta = xv[m][ii] - Dmu[ii];
        const float wv = Dw[ii];
        s1 += delta*delta*dinv;
        s2 += wv*wv*dinv;
        s3 += wv*dinv*delta;
        s4 += __logf(diag);
      }
    }
    s1 += __shfl_xor(s1, 16, 64); s1 += __shfl_xor(s1, 32, 64);
    s2 += __shfl_xor(s2, 16, 64); s2 += __shfl_xor(s2, 32, 64);
    s3 += __shfl_xor(s3, 16, 64); s3 += __shfl_xor(s3, 32, 64);
    s4 += __shfl_xor(s4, 16, 64); s4 += __shfl_xor(s4, 32, 64);
    const float cap = 1.f + s2;
    const float maha = s1 - s3*s3*rcpf(cap);
    const float logdet = s4 + __logf(cap);
    nll_acc += 0.5f*(64.f*LOG2PI_ + logdet + maha);
  }
  #pragma unroll
  for (int m = 1; m < 64; m <<= 1) nll_acc += __shfl_xor(nll_acc, m, 64);
  if (l == 0) atomicAdd(&out[0], nll_acc * 0.25f * (1.f/(float)Bb));
}

} // namespace

extern "C" void kernel_launch(void* const* d_in, const int* in_sizes, int n_in,
                              void* d_out, int out_size, void* d_ws, size_t ws_size,
                              hipStream_t stream)
{
  InPtrs ip;
  for (int i = 0; i < 42; ++i) ip.p[i] = (const float*)d_in[i];
  float* out = (float*)d_out;

  // workspace: 5 fp16 state arrays, layout [T][B][16] (32 MB each, 160 MB total)
  const size_t SZ = (size_t)Tt * Bb * 16;
  _Float16* hf  = (_Float16*)d_ws;
  _Float16* hb  = hf  + SZ;
  _Float16* hz  = hb  + SZ;
  _Float16* hgz = hz  + SZ;
  _Float16* hgr = hgz + SZ;

  zero2<<<1, 64, 0, stream>>>(out);
  dim3 gb(Bb/16, 2);
  bigru<<<gb, 128, 0, stream>>>(ip, hf, hb);
  vae_seq<<<Bb/16, 192, 0, stream>>>(ip, hf, hb, hz, hgz, hgr);
  kl_epi<<<1024, 256, 0, stream>>>(ip, hz, hgz, out);
  nll_epi<<<1024, 256, 0, stream>>>(ip, hgr, out);
}

// Round 2
// 1029.101 us; speedup vs baseline: 1.5845x; 1.0363x over previous
//
#include <hip/hip_runtime.h>

namespace {

typedef __attribute__((ext_vector_type(4))) _Float16 half4v;
typedef __attribute__((ext_vector_type(4))) float   float4v;
typedef unsigned int u32;

#define MFMA16(a,b,c) __builtin_amdgcn_mfma_f32_16x16x16f16((a),(b),(c),0,0,0)

constexpr int Bb = 2048;
constexpr int Tt = 512;
constexpr float LOG2PI_ = 1.8378770664093453f;

struct InPtrs { const float* p[42]; };

__device__ __forceinline__ float rcpf(float x){ return __builtin_amdgcn_rcpf(x); }
__device__ __forceinline__ float sigm(float x){ return rcpf(1.0f + __expf(-x)); }
__device__ __forceinline__ float tanh_(float x){ return 1.0f - 2.0f*rcpf(1.0f + __expf(2.0f*x)); }

// LDS-only barrier: waits lgkmcnt(0) but does NOT drain vmcnt, so global
// prefetch loads / streaming stores stay in flight across the barrier.
__device__ __forceinline__ void barrier_lds(){
  asm volatile("s_waitcnt lgkmcnt(0)" ::: "memory");
  __builtin_amdgcn_s_barrier();
  asm volatile("" ::: "memory");
}

__global__ void zero2(float* out){ if (threadIdx.x < 2) out[threadIdx.x] = 0.f; }

__device__ __forceinline__ void gru_update(const float4v& Dr, const float4v& Dz,
                                           const float4v& Dn, const float4v& Dh, half4v& hB){
  #pragma unroll
  for (int i = 0; i < 4; ++i){
    const float rr = sigm(Dr[i]);
    const float zz = sigm(Dz[i]);
    const float nn = tanh_(Dn[i] + rr*Dh[i]);
    const float hp = (float)hB[i];
    hB[i] = (_Float16)(nn + zz*(hp - nn));
  }
}

__device__ __forceinline__ half4v relu_pack(const float4v& D){
  half4v o;
  #pragma unroll
  for (int i = 0; i < 4; ++i) o[i] = (_Float16)fmaxf(D[i], 0.f);
  return o;
}

// ================= Phase 1: bi-GRU, producer/consumer =================
constexpr int CH = 8;
constexpr int NCH = Tt / CH;   // 64

__global__ __launch_bounds__(128,1) void bigru(InPtrs ip, _Float16* __restrict__ hf,
                                               _Float16* __restrict__ hb)
{
  const int tid = threadIdx.x;
  const int w = tid >> 6;
  const int l = tid & 63, r = l & 15, q = l >> 4;
  const int dir = blockIdx.y;
  const int base = blockIdx.x * 16;

  const float* __restrict__ x   = ip.p[0];
  const float* __restrict__ Wih = dir ? ip.p[6] : ip.p[2];
  const float* __restrict__ Whh = dir ? ip.p[7] : ip.p[3];
  const float* __restrict__ bih = dir ? ip.p[8] : ip.p[4];
  const float* __restrict__ bhh = dir ? ip.p[9] : ip.p[5];
  _Float16* __restrict__ hout = dir ? hb : hf;

  __shared__ __align__(16) float giS[2][CH][64][12];   // 48 KB

  half4v Wi[3][4];            // producer
  float  b0[4], b1[4], b2[4];
  float4v xp[CH][4];          // 8-step prefetch ring
  half4v Wh[3];               // consumer
  float  bh2[4];
  half4v hB = {0,0,0,0};
  const float* xrow = x + (size_t)(base + r) * Tt * 64;

  if (w == 1){
    #pragma unroll
    for (int rt = 0; rt < 3; ++rt)
      #pragma unroll
      for (int kt = 0; kt < 4; ++kt)
        #pragma unroll
        for (int j = 0; j < 4; ++j)
          Wi[rt][kt][j] = (_Float16)Wih[(rt*16 + r)*64 + kt*16 + q*4 + j];
    #pragma unroll
    for (int i = 0; i < 4; ++i){
      const int row = q*4 + i;
      b0[i] = bih[row]      + bhh[row];
      b1[i] = bih[16 + row] + bhh[16 + row];
      b2[i] = bih[32 + row];
    }
    #pragma unroll
    for (int s = 0; s < CH; ++s){
      const int tn = dir ? Tt-1-s : s;
      #pragma unroll
      for (int kt = 0; kt < 4; ++kt)
        xp[s][kt] = *(const float4v*)(xrow + (size_t)tn*64 + kt*16 + q*4);
    }
  } else {
    #pragma unroll
    for (int rt = 0; rt < 3; ++rt)
      #pragma unroll
      for (int j = 0; j < 4; ++j)
        Wh[rt][j] = (_Float16)Whh[(rt*16 + r)*16 + q*4 + j];
    #pragma unroll
    for (int i = 0; i < 4; ++i) bh2[i] = bhh[32 + q*4 + i];
  }

  for (int c = 0; c < NCH; ++c){
    if (w == 1){
      #pragma unroll
      for (int st = 0; st < CH; ++st){
        const int tg = c*CH + st;
        half4v xB[4];
        #pragma unroll
        for (int kt = 0; kt < 4; ++kt)
          #pragma unroll
          for (int j = 0; j < 4; ++j) xB[kt][j] = (_Float16)xp[st][kt][j];
        const int tp = tg + CH;
        if (tp < Tt){
          const int tn = dir ? Tt-1-tp : tp;
          #pragma unroll
          for (int kt = 0; kt < 4; ++kt)
            xp[st][kt] = *(const float4v*)(xrow + (size_t)tn*64 + kt*16 + q*4);
        }
        float4v A0 = {b0[0],b0[1],b0[2],b0[3]};
        float4v A1 = {b1[0],b1[1],b1[2],b1[3]};
        float4v A2 = {b2[0],b2[1],b2[2],b2[3]};
        #pragma unroll
        for (int kt = 0; kt < 4; ++kt){
          A0 = MFMA16(Wi[0][kt], xB[kt], A0);
          A1 = MFMA16(Wi[1][kt], xB[kt], A1);
          A2 = MFMA16(Wi[2][kt], xB[kt], A2);
        }
        float* o = &giS[c&1][st][l][0];
        *(float4v*)(o + 0) = A0;
        *(float4v*)(o + 4) = A1;
        *(float4v*)(o + 8) = A2;
      }
    }
    barrier_lds();
    if (w == 0){
      // unrolled so all 24 ds_reads of the chunk issue immediately after the
      // barrier; hB's dependent chain then runs without per-step LDS latency.
      #pragma unroll
      for (int st = 0; st < CH; ++st){
        const int tg = c*CH + st;
        const int t = dir ? Tt-1-tg : tg;
        const float* gi = &giS[c&1][st][l][0];
        float4v A0 = *(const float4v*)(gi + 0);
        float4v A1 = *(const float4v*)(gi + 4);
        float4v A2 = *(const float4v*)(gi + 8);
        float4v Dh = {bh2[0],bh2[1],bh2[2],bh2[3]};
        A0 = MFMA16(Wh[0], hB, A0);
        A1 = MFMA16(Wh[1], hB, A1);
        Dh = MFMA16(Wh[2], hB, Dh);
        gru_update(A0, A1, A2, Dh, hB);
        *(half4v*)(hout + (((size_t)t*Bb + base + r) << 4) + q*4) = hB;
      }
    }
  }
}

// ================= Phase 3a: sequential VAE recurrences only =================
// 3-wave skewed pipeline, one lgkm-only barrier/iter, unrolled x4 so wave A's
// hf/hb/eps prefetch is a depth-4 register ring (statically indexed).
// Wave A accumulation order: hr, hl (prefetched, ready) -> hz -> z LAST, so the
// chain from z (produced by the inf head) is a single MFMA latency.
__global__ __launch_bounds__(192,1) void vae_seq(InPtrs ip, const _Float16* __restrict__ hf,
                                                 const _Float16* __restrict__ hb,
                                                 _Float16* __restrict__ hz,
                                                 _Float16* __restrict__ hgz,
                                                 _Float16* __restrict__ hgr)
{
  const int tid = threadIdx.x;
  const int w = tid / 64;
  const int l = tid & 63, r = l & 15, q = l >> 4;
  const int base = blockIdx.x * 16;
  const int row0 = q*4;

  __shared__ u32 zS[3][2][64];
  for (int i = tid; i < 3*2*64; i += 192) ((u32*)zS)[i] = 0u;
  barrier_lds();

  // ---- per-wave persistent state ----
  // wave A
  half4v WizA[3][3], WhzA[3], I1A, I2A, IMuA, ICovA;
  float bz0[4], bz1[4], bzn[4], bzh[4], bI1v[4], bI2v[4], bIMu[4], bICov[4];
  half4v hzB = {0,0,0,0}, zB = {0,0,0,0};
  half4v hrR[4], hlR[4];     // depth-4 prefetch ring
  float4v eR[4];
  // wave B
  half4v WgzA[3], WhgzA[3];
  float bg0[4], bg1[4], bgn[4], bgh[4];
  half4v hgzB = {0,0,0,0};
  // wave C
  half4v WgrA[3], WhgrA[3];
  float br0[4], br1[4], brn[4], brh[4];
  half4v hgrB = {0,0,0,0};

  const float* erow = ip.p[1] + (size_t)(base + r) * Tt * 10;

  if (w == 0){
    #pragma unroll
    for (int rt = 0; rt < 3; ++rt)
      #pragma unroll
      for (int kt = 0; kt < 3; ++kt)
        #pragma unroll
        for (int j = 0; j < 4; ++j){
          const int k = kt*16 + q*4 + j;
          int c;
          if (kt == 0) c = (k < 10) ? k : -1;
          else if (kt == 1) c = 10 + (k - 16);
          else c = 26 + (k - 32);
          WizA[rt][kt][j] = (c >= 0) ? (_Float16)ip.p[10][(rt*16 + r)*42 + c] : (_Float16)0.f;
        }
    #pragma unroll
    for (int rt = 0; rt < 3; ++rt)
      #pragma unroll
      for (int j = 0; j < 4; ++j)
        WhzA[rt][j] = (_Float16)ip.p[11][(rt*16 + r)*16 + q*4 + j];
    #pragma unroll
    for (int j = 0; j < 4; ++j){
      const int k = q*4 + j;
      I1A[j]  = (_Float16)ip.p[14][r*16 + k];
      I2A[j]  = (_Float16)ip.p[16][r*16 + k];
      IMuA[j] = (r < 10) ? (_Float16)ip.p[18][r*16 + k] : (_Float16)0.f;
      ICovA[j]= (r < 10) ? (_Float16)ip.p[20][r*16 + k] : (_Float16)0.f;
    }
    #pragma unroll
    for (int i = 0; i < 4; ++i){
      const int row = row0 + i;
      bz0[i] = ip.p[12][row]    + ip.p[13][row];
      bz1[i] = ip.p[12][16+row] + ip.p[13][16+row];
      bzn[i] = ip.p[12][32+row];
      bzh[i] = ip.p[13][32+row];
      bI1v[i] = ip.p[15][row];  bI2v[i] = ip.p[17][row];
      bIMu[i]  = (row < 10) ? ip.p[19][row] : 0.f;
      bICov[i] = (row < 10) ? ip.p[21][row] : 0.f;
    }
    // preload ring slots for steps 0..3
    #pragma unroll
    for (int s = 0; s < 4; ++s){
      if (s >= 1) hrR[s] = *(const half4v*)(hf + (((size_t)(s-1)*Bb + base + r) << 4) + q*4);
      else { half4v z0 = {0,0,0,0}; hrR[s] = z0; }
      hlR[s] = *(const half4v*)(hb + (((size_t)(s+1)*Bb + base + r) << 4) + q*4);
      float4v et;
      #pragma unroll
      for (int ii = 0; ii < 4; ++ii) et[ii] = (row0 + ii < 10) ? erow[s*10 + row0 + ii] : 0.f;
      eR[s] = et;
    }
  } else if (w == 1){
    #pragma unroll
    for (int rt = 0; rt < 3; ++rt)
      #pragma unroll
      for (int j = 0; j < 4; ++j){
        const int k = q*4 + j;
        WgzA[rt][j]  = (k < 10) ? (_Float16)ip.p[22][(rt*16 + r)*10 + k] : (_Float16)0.f;
        WhgzA[rt][j] = (_Float16)ip.p[23][(rt*16 + r)*16 + k];
      }
    #pragma unroll
    for (int i = 0; i < 4; ++i){
      const int row = row0 + i;
      bg0[i] = ip.p[24][row]    + ip.p[25][row];
      bg1[i] = ip.p[24][16+row] + ip.p[25][16+row];
      bgn[i] = ip.p[24][32+row];
      bgh[i] = ip.p[25][32+row];
    }
  } else {
    #pragma unroll
    for (int rt = 0; rt < 3; ++rt)
      #pragma unroll
      for (int j = 0; j < 4; ++j){
        const int k = q*4 + j;
        WgrA[rt][j]  = (k < 10) ? (_Float16)ip.p[34][(rt*16 + r)*10 + k] : (_Float16)0.f;
        WhgrA[rt][j] = (_Float16)ip.p[35][(rt*16 + r)*16 + k];
      }
    #pragma unroll
    for (int i = 0; i < 4; ++i){
      const int row = row0 + i;
      br0[i] = ip.p[36][row]    + ip.p[37][row];
      br1[i] = ip.p[36][16+row] + ip.p[37][16+row];
      brn[i] = ip.p[36][32+row];
      brh[i] = ip.p[37][32+row];
    }
  }

  // ---- pipeline loop: 516 iters (= 4*129), one lgkm-only barrier per iter ----
  for (int ib = 0; ib < Tt + 4; ib += 4){
    #pragma unroll
    for (int k = 0; k < 4; ++k){
      const int i = ib + k;
      if (w == 0){
        if (i < Tt){
          const half4v hrB = hrR[k], hlB = hlR[k];
          const float4v ev = eR[k];
          // prefetch step i+4 into the just-freed slot (static index k)
          const int f = i + 4;
          if (f < Tt){
            hrR[k] = *(const half4v*)(hf + (((size_t)(f-1)*Bb + base + r) << 4) + q*4);
            if (f <= Tt-2) hlR[k] = *(const half4v*)(hb + (((size_t)(f+1)*Bb + base + r) << 4) + q*4);
            else { half4v z0 = {0,0,0,0}; hlR[k] = z0; }
            float4v et;
            #pragma unroll
            for (int ii = 0; ii < 4; ++ii) et[ii] = (row0 + ii < 10) ? erow[f*10 + row0 + ii] : 0.f;
            eR[k] = et;
          }
          // accumulate: hr, hl (ready) -> hz -> z last
          float4v Dr = {bz0[0],bz0[1],bz0[2],bz0[3]};
          float4v Dz = {bz1[0],bz1[1],bz1[2],bz1[3]};
          float4v Dn = {bzn[0],bzn[1],bzn[2],bzn[3]};
          float4v Dh = {bzh[0],bzh[1],bzh[2],bzh[3]};
          Dr = MFMA16(WizA[0][1], hrB, Dr); Dr = MFMA16(WizA[0][2], hlB, Dr);
          Dz = MFMA16(WizA[1][1], hrB, Dz); Dz = MFMA16(WizA[1][2], hlB, Dz);
          Dn = MFMA16(WizA[2][1], hrB, Dn); Dn = MFMA16(WizA[2][2], hlB, Dn);
          Dr = MFMA16(WhzA[0], hzB, Dr);
          Dz = MFMA16(WhzA[1], hzB, Dz);
          Dh = MFMA16(WhzA[2], hzB, Dh);
          Dr = MFMA16(WizA[0][0], zB, Dr);
          Dz = MFMA16(WizA[1][0], zB, Dz);
          Dn = MFMA16(WizA[2][0], zB, Dn);
          gru_update(Dr, Dz, Dn, Dh, hzB);
          *(half4v*)(hz + (((size_t)i*Bb + base + r) << 4) + q*4) = hzB;

          float4v H1 = {bI1v[0],bI1v[1],bI1v[2],bI1v[3]};
          H1 = MFMA16(I1A, hzB, H1);
          const half4v h1B = relu_pack(H1);
          float4v H2 = {bI2v[0],bI2v[1],bI2v[2],bI2v[3]};
          H2 = MFMA16(I2A, h1B, H2);
          const half4v h2B = relu_pack(H2);
          float4v Qmu  = {bIMu[0],bIMu[1],bIMu[2],bIMu[3]};
          float4v Qpre = {bICov[0],bICov[1],bICov[2],bICov[3]};
          Qmu  = MFMA16(IMuA,  h2B, Qmu);
          Qpre = MFMA16(ICovA, h2B, Qpre);

          const int slot = i % 3;
          #pragma unroll
          for (int ii = 0; ii < 4; ++ii){
            const float qs = __expf(Qpre[ii]);
            zB[ii] = (_Float16)(Qmu[ii] + qs*ev[ii]);
          }
          union { half4v h; u32 u[2]; } zc; zc.h = zB;
          zS[slot][0][l] = zc.u[0];
          zS[slot][1][l] = zc.u[1];
        }
      } else if (w == 1){
        if (i >= 1 && i <= Tt){
          const int s = i - 1;
          const int sp = (s - 1 + 3) % 3;
          union { half4v h; u32 u[2]; } zc;
          zc.u[0] = zS[sp][0][l]; zc.u[1] = zS[sp][1][l];
          const half4v zPrev = zc.h;

          float4v Er = {bg0[0],bg0[1],bg0[2],bg0[3]};
          float4v Ez = {bg1[0],bg1[1],bg1[2],bg1[3]};
          float4v En = {bgn[0],bgn[1],bgn[2],bgn[3]};
          float4v Eh = {bgh[0],bgh[1],bgh[2],bgh[3]};
          Er = MFMA16(WgzA[0], zPrev, Er); Er = MFMA16(WhgzA[0], hgzB, Er);
          Ez = MFMA16(WgzA[1], zPrev, Ez); Ez = MFMA16(WhgzA[1], hgzB, Ez);
          En = MFMA16(WgzA[2], zPrev, En);
          Eh = MFMA16(WhgzA[2], hgzB, Eh);
          gru_update(Er, Ez, En, Eh, hgzB);
          *(half4v*)(hgz + (((size_t)s*Bb + base + r) << 4) + q*4) = hgzB;
        }
      } else {
        if (i >= 2 && i < Tt + 2){
          const int u = i - 2;
          union { half4v h; u32 uu[2]; } zc;
          zc.uu[0] = zS[u % 3][0][l]; zc.uu[1] = zS[u % 3][1][l];
          const half4v zU = zc.h;

          float4v Fr = {br0[0],br0[1],br0[2],br0[3]};
          float4v Fz = {br1[0],br1[1],br1[2],br1[3]};
          float4v Fn = {brn[0],brn[1],brn[2],brn[3]};
          float4v Fh = {brh[0],brh[1],brh[2],brh[3]};
          Fr = MFMA16(WgrA[0], zU, Fr); Fr = MFMA16(WhgrA[0], hgrB, Fr);
          Fz = MFMA16(WgrA[1], zU, Fz); Fz = MFMA16(WhgrA[1], hgrB, Fz);
          Fn = MFMA16(WgrA[2], zU, Fn);
          Fh = MFMA16(WhgrA[2], hgrB, Fh);
          gru_update(Fr, Fz, Fn, Fh, hgrB);
          *(half4v*)(hgr + (((size_t)u*Bb + base + r) << 4) + q*4) = hgrB;
        }
      }
      barrier_lds();
    }
  }
}

// ================= Phase 3b: merged parallel epilogue =================
// Blocks [0,1024): KL (inf head from h_z + genz head from h_gz).
// Blocks [1024,2048): NLL (genr head from h_gr + low-rank Gaussian vs x).
// Co-scheduling overlaps KL's compute-heavy phase with NLL's memory-heavy phase.
__global__ __launch_bounds__(256,2) void epi(InPtrs ip, const _Float16* __restrict__ hz,
                                             const _Float16* __restrict__ hgz,
                                             const _Float16* __restrict__ hgr,
                                             float* __restrict__ out)
{
  const int tid = threadIdx.x;
  const int l = tid & 63, r = l & 15, q = l >> 4;
  const int row0 = q*4;

  if (blockIdx.x < 1024){
    const int wid = blockIdx.x * 4 + (tid >> 6);   // 4096 waves
    const int u0 = wid * 16;

    half4v I1A, I2A, IMuA, ICovA, Z1A, Z2A, ZMuA, ZCovA;
    float bI1v[4], bI2v[4], bIMu[4], bICov[4], bZ1v[4], bZ2v[4], bZMu[4], bZCov[4];
    #pragma unroll
    for (int j = 0; j < 4; ++j){
      const int k = q*4 + j;
      I1A[j]  = (_Float16)ip.p[14][r*16 + k];
      I2A[j]  = (_Float16)ip.p[16][r*16 + k];
      IMuA[j] = (r < 10) ? (_Float16)ip.p[18][r*16 + k] : (_Float16)0.f;
      ICovA[j]= (r < 10) ? (_Float16)ip.p[20][r*16 + k] : (_Float16)0.f;
      Z1A[j]  = (_Float16)ip.p[26][r*16 + k];
      Z2A[j]  = (_Float16)ip.p[28][r*16 + k];
      ZMuA[j] = (r < 10) ? (_Float16)ip.p[30][r*16 + k] : (_Float16)0.f;
      ZCovA[j]= (r < 10) ? (_Float16)ip.p[32][r*16 + k] : (_Float16)0.f;
    }
    #pragma unroll
    for (int i = 0; i < 4; ++i){
      const int row = row0 + i;
      bI1v[i] = ip.p[15][row];  bI2v[i] = ip.p[17][row];
      bIMu[i]  = (row < 10) ? ip.p[19][row] : 0.f;
      bICov[i] = (row < 10) ? ip.p[21][row] : 0.f;
      bZ1v[i] = ip.p[27][row];  bZ2v[i] = ip.p[29][row];
      bZMu[i]  = (row < 10) ? ip.p[31][row] : 0.f;
      bZCov[i] = (row < 10) ? ip.p[33][row] : 0.f;
    }

    float kl_acc = 0.f;
    for (int k = 0; k < 16; ++k){
      const int u = u0 + k;
      const int tile = u >> 9, t = u & 511;
      const size_t off = (((size_t)t*Bb + tile*16 + r) << 4) + q*4;
      const half4v hzB  = *(const half4v*)(hz  + off);
      const half4v hgzB = *(const half4v*)(hgz + off);

      float4v H1 = {bI1v[0],bI1v[1],bI1v[2],bI1v[3]};
      H1 = MFMA16(I1A, hzB, H1);
      const half4v h1B = relu_pack(H1);
      float4v H2 = {bI2v[0],bI2v[1],bI2v[2],bI2v[3]};
      H2 = MFMA16(I2A, h1B, H2);
      const half4v h2B = relu_pack(H2);
      float4v Qmu  = {bIMu[0],bIMu[1],bIMu[2],bIMu[3]};
      float4v Qpre = {bICov[0],bICov[1],bICov[2],bICov[3]};
      Qmu  = MFMA16(IMuA,  h2B, Qmu);
      Qpre = MFMA16(ICovA, h2B, Qpre);

      float4v G1 = {bZ1v[0],bZ1v[1],bZ1v[2],bZ1v[3]};
      G1 = MFMA16(Z1A, hgzB, G1);
      const half4v g1B = relu_pack(G1);
      float4v G2 = {bZ2v[0],bZ2v[1],bZ2v[2],bZ2v[3]};
      G2 = MFMA16(Z2A, g1B, G2);
      const half4v g2B = relu_pack(G2);
      float4v Pmu  = {bZMu[0],bZMu[1],bZMu[2],bZMu[3]};
      float4v Ppre = {bZCov[0],bZCov[1],bZCov[2],bZCov[3]};
      Pmu  = MFMA16(ZMuA,  g2B, Pmu);
      Ppre = MFMA16(ZCovA, g2B, Ppre);

      #pragma unroll
      for (int ii = 0; ii < 4; ++ii){
        const float qs = __expf(Qpre[ii]);
        const float dm = Qmu[ii] - Pmu[ii];
        kl_acc += (Ppre[ii] - Qpre[ii]) + (qs*qs + dm*dm)*0.5f*__expf(-2.f*Ppre[ii]) - 0.5f;
      }
    }
    #pragma unroll
    for (int m = 1; m < 64; m <<= 1) kl_acc += __shfl_xor(kl_acc, m, 64);
    if (l == 0) atomicAdd(&out[1], kl_acc * (1.f/(float)Bb));
  } else {
    const int wid = (blockIdx.x - 1024) * 4 + (tid >> 6);   // 4096 waves
    const int u0 = wid * 16;

    half4v R1A, R2A[12];
    float bR1v[4], bR2v[12][4];
    #pragma unroll
    for (int j = 0; j < 4; ++j){
      const int k = q*4 + j;
      R1A[j] = (_Float16)ip.p[38][r*16 + k];
      #pragma unroll
      for (int m = 0; m < 12; ++m)
        R2A[m][j] = (_Float16)ip.p[40][(m*16 + r)*16 + k];
    }
    #pragma unroll
    for (int i = 0; i < 4; ++i){
      const int row = row0 + i;
      bR1v[i] = ip.p[39][row];
      #pragma unroll
      for (int m = 0; m < 12; ++m) bR2v[m][i] = ip.p[41][m*16 + row];
    }

    float nll_acc = 0.f;
    for (int k = 0; k < 16; ++k){
      const int u = u0 + k;
      const int tile = u >> 9, t = u & 511;
      const half4v hgrB = *(const half4v*)(hgr + (((size_t)t*Bb + tile*16 + r) << 4) + q*4);
      const float* xrow = ip.p[0] + ((size_t)(tile*16 + r) * Tt + t) * 64;
      float4v xv[4];
      #pragma unroll
      for (int m = 0; m < 4; ++m) xv[m] = *(const float4v*)(xrow + m*16 + q*4);

      float4v R1D = {bR1v[0],bR1v[1],bR1v[2],bR1v[3]};
      R1D = MFMA16(R1A, hgrB, R1D);
      const half4v r1B = relu_pack(R1D);

      float s1 = 0.f, s2 = 0.f, s3 = 0.f, s4 = 0.f;
      #pragma unroll
      for (int m = 0; m < 4; ++m){
        float4v Dmu = {bR2v[m][0],bR2v[m][1],bR2v[m][2],bR2v[m][3]};
        float4v Ddp = {bR2v[4+m][0],bR2v[4+m][1],bR2v[4+m][2],bR2v[4+m][3]};
        float4v Dw  = {bR2v[8+m][0],bR2v[8+m][1],bR2v[8+m][2],bR2v[8+m][3]};
        Dmu = MFMA16(R2A[m],   r1B, Dmu);
        Ddp = MFMA16(R2A[4+m], r1B, Ddp);
        Dw  = MFMA16(R2A[8+m], r1B, Dw);
        #pragma unroll
        for (int ii = 0; ii < 4; ++ii){
          const float diag = __expf(Ddp[ii]) + 1e-4f;
          const float dinv = rcpf(diag);
          const float delta = xv[m][ii] - Dmu[ii];
          const float wv = Dw[ii];
          s1 += delta*delta*dinv;
          s2 += wv*wv*dinv;
          s3 += wv*dinv*delta;
          s4 += __logf(diag);
        }
      }
      s1 += __shfl_xor(s1, 16, 64); s1 += __shfl_xor(s1, 32, 64);
      s2 += __shfl_xor(s2, 16, 64); s2 += __shfl_xor(s2, 32, 64);
      s3 += __shfl_xor(s3, 16, 64); s3 += __shfl_xor(s3, 32, 64);
      s4 += __shfl_xor(s4, 16, 64); s4 += __shfl_xor(s4, 32, 64);
      const float cap = 1.f + s2;
      const float maha = s1 - s3*s3*rcpf(cap);
      const float logdet = s4 + __logf(cap);
      nll_acc += 0.5f*(64.f*LOG2PI_ + logdet + maha);
    }
    #pragma unroll
    for (int m = 1; m < 64; m <<= 1) nll_acc += __shfl_xor(nll_acc, m, 64);
    if (l == 0) atomicAdd(&out[0], nll_acc * 0.25f * (1.f/(float)Bb));
  }
}

} // namespace

extern "C" void kernel_launch(void* const* d_in, const int* in_sizes, int n_in,
                              void* d_out, int out_size, void* d_ws, size_t ws_size,
                              hipStream_t stream)
{
  InPtrs ip;
  for (int i = 0; i < 42; ++i) ip.p[i] = (const float*)d_in[i];
  float* out = (float*)d_out;

  const size_t SZ = (size_t)Tt * Bb * 16;
  _Float16* hf  = (_Float16*)d_ws;
  _Float16* hb  = hf  + SZ;
  _Float16* hz  = hb  + SZ;
  _Float16* hgz = hz  + SZ;
  _Float16* hgr = hgz + SZ;

  zero2<<<1, 64, 0, stream>>>(out);
  dim3 gb(Bb/16, 2);
  bigru<<<gb, 128, 0, stream>>>(ip, hf, hb);
  vae_seq<<<Bb/16, 192, 0, stream>>>(ip, hf, hb, hz, hgz, hgr);
  epi<<<2048, 256, 0, stream>>>(ip, hz, hgz, hgr, out);
}